// Round 6
// baseline (419.581 us; speedup 1.0000x reference)
//
#include <hip/hip_runtime.h>
#include <cstddef>

#define NB 256   // batch
#define NT 512   // time
#define ND 128   // input dim
#define NH 128   // hidden
#define NG 512   // 4*H
#define NM (NB * NT)     // 131072 rows of the input GEMM
#define NMP (NM + 64)    // padded G stride (f16 elems): breaks 2^18-byte L2 set aliasing

constexpr float F_EPS  = 1e-7f;
constexpr float F_TEMP = 0.1f;

typedef _Float16 h2_t __attribute__((ext_vector_type(2)));
typedef _Float16 h4_t __attribute__((ext_vector_type(4)));
typedef _Float16 h8_t __attribute__((ext_vector_type(8)));
typedef float    fx4  __attribute__((ext_vector_type(4)));

#if defined(__has_builtin)
#  if __has_builtin(__builtin_amdgcn_fdot2)
#    define FDOT2(a, b, c) __builtin_amdgcn_fdot2((a), (b), (c), false)
#  endif
#endif
#ifndef FDOT2
#  define FDOT2(a, b, c) ((c) + (float)(a)[0] * (float)(b)[0] + (float)(a)[1] * (float)(b)[1])
#endif

__device__ __forceinline__ float fexp2(float x) {
#if defined(__has_builtin)
#  if __has_builtin(__builtin_amdgcn_exp2f)
    return __builtin_amdgcn_exp2f(x);
#  else
    return exp2f(x);
#  endif
#else
    return exp2f(x);
#endif
}
__device__ __forceinline__ float frcp(float x) {
#if defined(__has_builtin)
#  if __has_builtin(__builtin_amdgcn_rcpf)
    return __builtin_amdgcn_rcpf(x);
#  else
    return 1.0f / x;
#  endif
#else
    return 1.0f / x;
#endif
}
__device__ __forceinline__ float ftanh(float x) {
    return 1.0f - 2.0f * frcp(1.0f + fexp2(x * 2.885390081777927f));
}
__device__ __forceinline__ float sig(float x) { return 1.0f / (1.0f + expf(-x)); }

// LDS-ordering-only barrier: does NOT drain vmcnt (global loads/stores stay in
// flight). lgkmcnt(0) orders our ds ops before the barrier; sched_barrier pins
// it (rule #18).
__device__ __forceinline__ void bar_lds() {
    asm volatile("s_waitcnt lgkmcnt(0)" ::: "memory");
    __builtin_amdgcn_sched_barrier(0);
    __builtin_amdgcn_s_barrier();
}

// ---------------- kernel 1: f32 -> f16 weight conversion + weight^2 sums ----------------
__global__ __launch_bounds__(256) void k_convert(const float* __restrict__ wih,
        const float* __restrict__ whh, _Float16* __restrict__ wih_h,
        _Float16* __restrict__ whh_h, float* __restrict__ partial) {
    int i = blockIdx.x * 256 + threadIdx.x;    // float4 index, 16384 total
    float4 a = ((const float4*)wih)[i];
    float4 b = ((const float4*)whh)[i];
    h4_t ah, bh;
    ah[0] = (_Float16)a.x; ah[1] = (_Float16)a.y; ah[2] = (_Float16)a.z; ah[3] = (_Float16)a.w;
    bh[0] = (_Float16)b.x; bh[1] = (_Float16)b.y; bh[2] = (_Float16)b.z; bh[3] = (_Float16)b.w;
    *(h4_t*)(wih_h + 4 * (size_t)i) = ah;
    *(h4_t*)(whh_h + 4 * (size_t)i) = bh;
    float sk = a.x * a.x + a.y * a.y + a.z * a.z + a.w * a.w;
    float sr = b.x * b.x + b.y * b.y + b.z * b.z + b.w * b.w;
    for (int off = 32; off; off >>= 1) {
        sk += __shfl_down(sk, off);
        sr += __shfl_down(sr, off);
    }
    if ((threadIdx.x & 63) == 0) {
        atomicAdd(partial + 0, sk);
        atomicAdd(partial + 1, sr);
    }
}

// ---------------- kernel 1b: finalize scalar regularization outputs ----------------
__global__ void k_tail(const float* __restrict__ bih, const float* __restrict__ bhh,
                       const float* __restrict__ pl, const float* __restrict__ plr,
                       const float* __restrict__ partial, float* __restrict__ out_tail) {
    __shared__ float red[8];
    int t = threadIdx.x;  // 512 threads
    float v = bih[t], w2 = bhh[t];
    float sb = v * v + w2 * w2;
    for (int off = 32; off; off >>= 1) sb += __shfl_down(sb, off);
    int wid = t >> 6, lane = t & 63;
    if (lane == 0) red[wid] = sb;
    __syncthreads();
    if (t == 0) {
        float SB = 0.f;
        for (int i = 0; i < 8; i++) SB += red[i];
        float SK = partial[0], SR = partial[1];
        float p  = sig(pl[0]);
        float pr = sig(plr[0]);
        float wr = 1e-6f * (SK / (1.f - p) + SR / (1.f - pr));
        float br = 1e-6f * SB;
        float ek = p * logf(p) + (1.f - p) * logf(1.f - p);
        float er = pr * logf(pr) + (1.f - pr) * logf(1.f - pr);
        float dr = 1e-5f * ((float)ND * ek + (float)NH * er);
        out_tail[0] = wr + br + dr;
        out_tail[1] = p;
        out_tail[2] = pr;
    }
}

// ---------------- kernel 2: f16 MFMA input GEMM (proven; only stride -> NMP) ---------
__global__ __launch_bounds__(256, 2) void k_gemm(const float* __restrict__ x,
        const _Float16* __restrict__ wih_h, const float* __restrict__ bih,
        const float* __restrict__ bhh, const float* __restrict__ pl,
        const float* __restrict__ unif_x, _Float16* __restrict__ Gp) {
    __shared__ _Float16 Alds[128 * 128];
    __shared__ _Float16 Wlds[128 * 128];
    __shared__ float sx[128];
    __shared__ float bsum[128];
    int t  = threadIdx.x;
    int m0 = blockIdx.x * 128;           // row block (within one batch b: 128 | 512)
    int j0 = blockIdx.y * 128;           // gate-col block
    int b  = m0 >> 9;

    float p = sig(pl[0]);
    if (t < 128) {
        float u  = unif_x[b * ND + t];
        float lg = logf(p + F_EPS) - logf(1.f - p + F_EPS)
                 + logf(u + F_EPS) - logf(1.f - u + F_EPS);
        float mk = 1.f - sig(lg / F_TEMP);
        sx[t] = mk / (1.f - p);
    } else {
        int j = t - 128;
        bsum[j] = bih[j0 + j] + bhh[j0 + j];
    }
    __syncthreads();

#pragma unroll
    for (int i = 0; i < 8; i++) {
        int s   = i * 256 + t;
        int row = s >> 4;                 // 0..127
        int s16 = s & 15;                 // 16B slot within row
        const float4* xp = (const float4*)(x + (size_t)(m0 + row) * ND + s16 * 8);
        float4 v0 = xp[0], v1 = xp[1];
        float4 s0 = *(const float4*)(sx + s16 * 8);
        float4 s1 = *(const float4*)(sx + s16 * 8 + 4);
        h8_t hv;
        hv[0] = (_Float16)(v0.x * s0.x); hv[1] = (_Float16)(v0.y * s0.y);
        hv[2] = (_Float16)(v0.z * s0.z); hv[3] = (_Float16)(v0.w * s0.w);
        hv[4] = (_Float16)(v1.x * s1.x); hv[5] = (_Float16)(v1.y * s1.y);
        hv[6] = (_Float16)(v1.z * s1.z); hv[7] = (_Float16)(v1.w * s1.w);
        *(h8_t*)(&Alds[(size_t)row * 128 + ((s16 ^ (row & 7)) << 3)]) = hv;
        h8_t wv = *(const h8_t*)(wih_h + (size_t)(j0 + row) * ND + s16 * 8);
        *(h8_t*)(&Wlds[(size_t)row * 128 + ((s16 ^ (row & 7)) << 3)]) = wv;
    }
    __syncthreads();

    int w  = t >> 6, l = t & 63;
    int lr = l & 15, lg = l >> 4;
    fx4 acc[2][8] = {};
#pragma unroll
    for (int kk = 0; kk < 4; kk++) {
        h8_t af[2], bf[8];
#pragma unroll
        for (int mt = 0; mt < 2; mt++) {
            int r = 32 * w + 16 * mt + lr;
            af[mt] = *(const h8_t*)(&Alds[(size_t)r * 128 + (((4 * kk + lg) ^ (r & 7)) << 3)]);
        }
#pragma unroll
        for (int nt = 0; nt < 8; nt++) {
            int r = 16 * nt + lr;
            bf[nt] = *(const h8_t*)(&Wlds[(size_t)r * 128 + (((4 * kk + lg) ^ (r & 7)) << 3)]);
        }
#pragma unroll
        for (int mt = 0; mt < 2; mt++)
#pragma unroll
            for (int nt = 0; nt < 8; nt++)
                acc[mt][nt] = __builtin_amdgcn_mfma_f32_16x16x32_f16(af[mt], bf[nt], acc[mt][nt], 0, 0, 0);
    }

#pragma unroll
    for (int mt = 0; mt < 2; mt++)
#pragma unroll
        for (int nt = 0; nt < 8; nt++) {
            int j = j0 + 16 * nt + lr;
            int m = m0 + 32 * w + 16 * mt + 4 * lg;
            float bv = bsum[16 * nt + lr];
            h4_t o;
#pragma unroll
            for (int q = 0; q < 4; q++) o[q] = (_Float16)(acc[mt][nt][q] + bv);
            *(h4_t*)(Gp + (size_t)j * NMP + m) = o;
        }
}

// ---------------- kernel 3: recurrence, 512 threads, ONE barrier per step ------------
// Block = batch b. Thread: lane l, wave wv; column n = wv*16 + (l&15), gate
// g = (l>>4)&3, gate row j = g*128 + n. The 4 gate-threads of a column share a
// wave -> gate exchange is 3 shfl_xor (no LDS, no 2nd barrier). c,h updated
// redundantly in all 4 lanes. hd double-buffered: step t reads hd[t&1], writes
// hd[(t&1)^1] -> single end-of-step barrier is race-free. W_hh row pinned in 64
// VGPRs; G in registers (h8 per 8 steps, padded NMP stride kills L2 aliasing).
__global__ __launch_bounds__(512, 1) void k_lstm(const _Float16* __restrict__ Gp,
        const _Float16* __restrict__ whh_h, const float* __restrict__ plr,
        const float* __restrict__ unif_h,
        float* __restrict__ xout, float* __restrict__ hlast) {
    __shared__ _Float16 hd[2][128];
    int b   = blockIdx.x;
    int tid = threadIdx.x;
    int l   = tid & 63;
    int wv  = tid >> 6;
    int n   = wv * 16 + (l & 15);    // hidden column owned
    int g   = (l >> 4) & 3;          // 0:i 1:f 2:g 3:o
    int j   = g * 128 + n;           // gate row

    h2_t w[64];
    {
        const _Float16* wr = whh_h + (size_t)j * NH;
#pragma unroll
        for (int i = 0; i < 16; i++) {
            h8_t a = *(const h8_t*)(wr + 8 * i);
#pragma unroll
            for (int q = 0; q < 4; q++)
                w[4 * i + q] = (h2_t){a[2 * q], a[2 * q + 1]};
        }
    }

    float pr = sig(plr[0]);
    float msk;
    {
        float u  = unif_h[b * NH + n];
        float lg = logf(pr + F_EPS) - logf(1.f - pr + F_EPS)
                 + logf(u + F_EPS) - logf(1.f - u + F_EPS);
        float mk = 1.f - sig(lg / F_TEMP);
        msk = mk / (1.f - pr);
    }
    float h = 0.f, c = 0.f;
    if (g == 0) hd[0][n] = (_Float16)0.f;

    // per-gate activation constants: act = B + A * rcp(1 + exp2(s*k1))
    const float k1 = (g == 2) ?  2.885390081777927f : -1.44269504088896f;
    const float Ac = (g == 2) ? -2.f : 1.f;
    const float Bc = (g == 2) ?  1.f : 0.f;

    const _Float16* gp = Gp + (size_t)j * NMP + (size_t)b * NT;
    float* xo = xout + (size_t)b * NT * NH + n;   // stored by g==0 lanes

    h8_t gcur = *(const h8_t*)(gp);
    __syncthreads();          // hd[0] init visible

    for (int w8 = 0; w8 < NT / 8; w8++) {
        // pin W_hh in VGPRs (loop-carried asm outputs can't be rematerialized)
#pragma unroll
        for (int i = 0; i < 64; i++) asm volatile("" : "+v"(w[i]));
        h8_t gnx = gcur;
        if (w8 + 1 < NT / 8)
            gnx = *(const h8_t*)(gp + 8 * (w8 + 1));   // in flight ~8 steps
#pragma unroll
        for (int e = 0; e < 8; e++) {
            const _Float16* hb = &hd[e & 1][0];        // read parity (w8*8 even)
            float a0 = 0.f, a1 = 0.f, a2 = 0.f, a3 = 0.f;
#pragma unroll
            for (int i = 0; i < 16; i++) {
                h8_t hv = *(const h8_t*)(hb + 8 * i);  // broadcast read
                a0 = FDOT2(((h2_t){hv[0], hv[1]}), w[4 * i + 0], a0);
                a1 = FDOT2(((h2_t){hv[2], hv[3]}), w[4 * i + 1], a1);
                a2 = FDOT2(((h2_t){hv[4], hv[5]}), w[4 * i + 2], a2);
                a3 = FDOT2(((h2_t){hv[6], hv[7]}), w[4 * i + 3], a3);
            }
            float s   = (float)gcur[e] + ((a0 + a1) + (a2 + a3));
            float act = Bc + Ac * frcp(1.f + fexp2(s * k1));
            // gather the other 3 gates' activations (same column, lanes l^16,l^32,l^48)
            float r1 = __shfl_xor(act, 16, 64);
            float r2 = __shfl_xor(act, 32, 64);
            float r3 = __shfl_xor(r1, 32, 64);
            // value of gate q sits in slot m = g ^ q of {act,r1,r2,r3}
            float iv = (g == 0) ? act : (g == 1) ? r1 : (g == 2) ? r2 : r3;
            float fv = (g == 1) ? act : (g == 0) ? r1 : (g == 3) ? r2 : r3;
            float gv = (g == 2) ? act : (g == 3) ? r1 : (g == 0) ? r2 : r3;
            float ov = (g == 3) ? act : (g == 2) ? r1 : (g == 1) ? r2 : r3;
            c = fv * c + iv * gv;
            h = ov * ftanh(c);
            if (g == 0) {
                hd[(e & 1) ^ 1][n] = (_Float16)(h * msk);
                xo[(size_t)(8 * w8 + e) * NH] = h;   // never drained by bar_lds
            }
            bar_lds();         // step-t hd writes visible; next step reads other buffer
        }
        gcur = gnx;
    }
    if (g == 0) hlast[(size_t)b * NH + n] = h;
}

extern "C" void kernel_launch(void* const* d_in, const int* in_sizes, int n_in,
                              void* d_out, int out_size, void* d_ws, size_t ws_size,
                              hipStream_t stream) {
    const float* x   = (const float*)d_in[0];
    const float* wih = (const float*)d_in[1];
    const float* whh = (const float*)d_in[2];
    const float* bih = (const float*)d_in[3];
    const float* bhh = (const float*)d_in[4];
    const float* pl  = (const float*)d_in[5];
    const float* plr = (const float*)d_in[6];
    const float* ux  = (const float*)d_in[7];
    const float* uh  = (const float*)d_in[8];

    float* out   = (float*)d_out;
    float* xout  = out;                                 // [B,T,H]
    float* hlast = out + (size_t)NB * NT * NH;          // [B,H]
    float* tail  = hlast + (size_t)NB * NH;             // reg, p, p_rec

    _Float16* G     = (_Float16*)d_ws;                               // [NG][NMP] f16
    _Float16* wih_h = (_Float16*)((char*)d_ws + (size_t)NG * NMP * 2);
    _Float16* whh_h = wih_h + (size_t)NG * ND;
    float*    partial = (float*)(whh_h + (size_t)NG * NH);           // 2 floats

    hipMemsetAsync(partial, 0, 2 * sizeof(float), stream);

    k_convert<<<64, 256, 0, stream>>>(wih, whh, wih_h, whh_h, partial);

    dim3 gg(NM / 128, NG / 128);
    k_gemm<<<gg, 256, 0, stream>>>(x, wih_h, bih, bhh, pl, ux, G);

    k_tail<<<1, 512, 0, stream>>>(bih, bhh, pl, plr, partial, tail);

    k_lstm<<<NB, 512, 0, stream>>>(G, whh_h, plr, uh, xout, hlast);
}

// Round 7
// 377.255 us; speedup vs baseline: 1.1122x; 1.1122x over previous
//
#include <hip/hip_runtime.h>
#include <cstddef>

#define NB 256   // batch
#define NT 512   // time
#define ND 128   // input dim
#define NH 128   // hidden
#define NG 512   // 4*H
#define NM (NB * NT)     // 131072 rows of the input GEMM
#define NMP (NM + 64)    // padded G stride (f16 elems): breaks 2^18-byte L2 set aliasing

constexpr float F_EPS  = 1e-7f;
constexpr float F_TEMP = 0.1f;

typedef _Float16 h2_t __attribute__((ext_vector_type(2)));
typedef _Float16 h4_t __attribute__((ext_vector_type(4)));
typedef _Float16 h8_t __attribute__((ext_vector_type(8)));
typedef float    fx4  __attribute__((ext_vector_type(4)));

#if defined(__has_builtin)
#  if __has_builtin(__builtin_amdgcn_fdot2)
#    define FDOT2(a, b, c) __builtin_amdgcn_fdot2((a), (b), (c), false)
#  endif
#endif
#ifndef FDOT2
#  define FDOT2(a, b, c) ((c) + (float)(a)[0] * (float)(b)[0] + (float)(a)[1] * (float)(b)[1])
#endif

__device__ __forceinline__ float fexp2(float x) {
#if defined(__has_builtin)
#  if __has_builtin(__builtin_amdgcn_exp2f)
    return __builtin_amdgcn_exp2f(x);
#  else
    return exp2f(x);
#  endif
#else
    return exp2f(x);
#endif
}
__device__ __forceinline__ float frcp(float x) {
#if defined(__has_builtin)
#  if __has_builtin(__builtin_amdgcn_rcpf)
    return __builtin_amdgcn_rcpf(x);
#  else
    return 1.0f / x;
#  endif
#else
    return 1.0f / x;
#endif
}
__device__ __forceinline__ float fsig(float x) {
    return frcp(1.0f + fexp2(x * -1.44269504088896f));
}
__device__ __forceinline__ float ftanh(float x) {
    return 1.0f - 2.0f * frcp(1.0f + fexp2(x * 2.885390081777927f));
}
__device__ __forceinline__ float sig(float x) { return 1.0f / (1.0f + expf(-x)); }

// LDS-ordering-only barrier: does NOT drain vmcnt (global loads/stores stay in
// flight). lgkmcnt(0) orders our ds ops before the barrier; sched_barrier pins
// it (rule #18).
__device__ __forceinline__ void bar_lds() {
    asm volatile("s_waitcnt lgkmcnt(0)" ::: "memory");
    __builtin_amdgcn_sched_barrier(0);
    __builtin_amdgcn_s_barrier();
}

// ---------------- kernel 1: f32 -> f16 weight conversion + weight^2 sums ----------------
__global__ __launch_bounds__(256) void k_convert(const float* __restrict__ wih,
        const float* __restrict__ whh, _Float16* __restrict__ wih_h,
        _Float16* __restrict__ whh_h, float* __restrict__ partial) {
    int i = blockIdx.x * 256 + threadIdx.x;    // float4 index, 16384 total
    float4 a = ((const float4*)wih)[i];
    float4 b = ((const float4*)whh)[i];
    h4_t ah, bh;
    ah[0] = (_Float16)a.x; ah[1] = (_Float16)a.y; ah[2] = (_Float16)a.z; ah[3] = (_Float16)a.w;
    bh[0] = (_Float16)b.x; bh[1] = (_Float16)b.y; bh[2] = (_Float16)b.z; bh[3] = (_Float16)b.w;
    *(h4_t*)(wih_h + 4 * (size_t)i) = ah;
    *(h4_t*)(whh_h + 4 * (size_t)i) = bh;
    float sk = a.x * a.x + a.y * a.y + a.z * a.z + a.w * a.w;
    float sr = b.x * b.x + b.y * b.y + b.z * b.z + b.w * b.w;
    for (int off = 32; off; off >>= 1) {
        sk += __shfl_down(sk, off);
        sr += __shfl_down(sr, off);
    }
    if ((threadIdx.x & 63) == 0) {
        atomicAdd(partial + 0, sk);
        atomicAdd(partial + 1, sr);
    }
}

// ---------------- kernel 1b: finalize scalar regularization outputs ----------------
__global__ void k_tail(const float* __restrict__ bih, const float* __restrict__ bhh,
                       const float* __restrict__ pl, const float* __restrict__ plr,
                       const float* __restrict__ partial, float* __restrict__ out_tail) {
    __shared__ float red[8];
    int t = threadIdx.x;  // 512 threads
    float v = bih[t], w2 = bhh[t];
    float sb = v * v + w2 * w2;
    for (int off = 32; off; off >>= 1) sb += __shfl_down(sb, off);
    int wid = t >> 6, lane = t & 63;
    if (lane == 0) red[wid] = sb;
    __syncthreads();
    if (t == 0) {
        float SB = 0.f;
        for (int i = 0; i < 8; i++) SB += red[i];
        float SK = partial[0], SR = partial[1];
        float p  = sig(pl[0]);
        float pr = sig(plr[0]);
        float wr = 1e-6f * (SK / (1.f - p) + SR / (1.f - pr));
        float br = 1e-6f * SB;
        float ek = p * logf(p) + (1.f - p) * logf(1.f - p);
        float er = pr * logf(pr) + (1.f - pr) * logf(1.f - pr);
        float dr = 1e-5f * ((float)ND * ek + (float)NH * er);
        out_tail[0] = wr + br + dr;
        out_tail[1] = p;
        out_tail[2] = pr;
    }
}

// ---------------- kernel 2: f16 MFMA input GEMM (proven; stride NMP) ----------------
__global__ __launch_bounds__(256, 2) void k_gemm(const float* __restrict__ x,
        const _Float16* __restrict__ wih_h, const float* __restrict__ bih,
        const float* __restrict__ bhh, const float* __restrict__ pl,
        const float* __restrict__ unif_x, _Float16* __restrict__ Gp) {
    __shared__ _Float16 Alds[128 * 128];
    __shared__ _Float16 Wlds[128 * 128];
    __shared__ float sx[128];
    __shared__ float bsum[128];
    int t  = threadIdx.x;
    int m0 = blockIdx.x * 128;           // row block (within one batch b: 128 | 512)
    int j0 = blockIdx.y * 128;           // gate-col block
    int b  = m0 >> 9;

    float p = sig(pl[0]);
    if (t < 128) {
        float u  = unif_x[b * ND + t];
        float lg = logf(p + F_EPS) - logf(1.f - p + F_EPS)
                 + logf(u + F_EPS) - logf(1.f - u + F_EPS);
        float mk = 1.f - sig(lg / F_TEMP);
        sx[t] = mk / (1.f - p);
    } else {
        int j = t - 128;
        bsum[j] = bih[j0 + j] + bhh[j0 + j];
    }
    __syncthreads();

#pragma unroll
    for (int i = 0; i < 8; i++) {
        int s   = i * 256 + t;
        int row = s >> 4;                 // 0..127
        int s16 = s & 15;                 // 16B slot within row
        const float4* xp = (const float4*)(x + (size_t)(m0 + row) * ND + s16 * 8);
        float4 v0 = xp[0], v1 = xp[1];
        float4 s0 = *(const float4*)(sx + s16 * 8);
        float4 s1 = *(const float4*)(sx + s16 * 8 + 4);
        h8_t hv;
        hv[0] = (_Float16)(v0.x * s0.x); hv[1] = (_Float16)(v0.y * s0.y);
        hv[2] = (_Float16)(v0.z * s0.z); hv[3] = (_Float16)(v0.w * s0.w);
        hv[4] = (_Float16)(v1.x * s1.x); hv[5] = (_Float16)(v1.y * s1.y);
        hv[6] = (_Float16)(v1.z * s1.z); hv[7] = (_Float16)(v1.w * s1.w);
        *(h8_t*)(&Alds[(size_t)row * 128 + ((s16 ^ (row & 7)) << 3)]) = hv;
        h8_t wv = *(const h8_t*)(wih_h + (size_t)(j0 + row) * ND + s16 * 8);
        *(h8_t*)(&Wlds[(size_t)row * 128 + ((s16 ^ (row & 7)) << 3)]) = wv;
    }
    __syncthreads();

    int w  = t >> 6, l = t & 63;
    int lr = l & 15, lg = l >> 4;
    fx4 acc[2][8] = {};
#pragma unroll
    for (int kk = 0; kk < 4; kk++) {
        h8_t af[2], bf[8];
#pragma unroll
        for (int mt = 0; mt < 2; mt++) {
            int r = 32 * w + 16 * mt + lr;
            af[mt] = *(const h8_t*)(&Alds[(size_t)r * 128 + (((4 * kk + lg) ^ (r & 7)) << 3)]);
        }
#pragma unroll
        for (int nt = 0; nt < 8; nt++) {
            int r = 16 * nt + lr;
            bf[nt] = *(const h8_t*)(&Wlds[(size_t)r * 128 + (((4 * kk + lg) ^ (r & 7)) << 3)]);
        }
#pragma unroll
        for (int mt = 0; mt < 2; mt++)
#pragma unroll
            for (int nt = 0; nt < 8; nt++)
                acc[mt][nt] = __builtin_amdgcn_mfma_f32_16x16x32_f16(af[mt], bf[nt], acc[mt][nt], 0, 0, 0);
    }

#pragma unroll
    for (int mt = 0; mt < 2; mt++)
#pragma unroll
        for (int nt = 0; nt < 8; nt++) {
            int j = j0 + 16 * nt + lr;
            int m = m0 + 32 * w + 16 * mt + 4 * lg;
            float bv = bsum[16 * nt + lr];
            h4_t o;
#pragma unroll
            for (int q = 0; q < 4; q++) o[q] = (_Float16)(acc[mt][nt][q] + bv);
            *(h4_t*)(Gp + (size_t)j * NMP + m) = o;
        }
}

// ---------------- kernel 3: recurrence, 256 threads (column x k-half) ----------------
// Block = batch b. Thread: wave wv, lane l; column n = wv*32 + (l&31), k-half
// = l>>5. Each thread owns ALL 4 gate rows of its column for its k-half:
// w[4][32] h2 = 128 VGPRs (pinned). Per step: 8 broadcast ds_read_b128 (its
// 128B half of hd), 128 fdot2, 4 shfl_xor(32) to combine halves (symmetric ->
// both halves hold identical full sums; no gate exchange needed at all),
// 4 fast activations, c/h update, 1 LDS-only barrier. G: 4 register streams
// (h8 per 8 steps); lanes l and l^32 read identical G addresses (merged).
__global__ __launch_bounds__(256, 1) void k_lstm(const _Float16* __restrict__ Gp,
        const _Float16* __restrict__ whh_h, const float* __restrict__ plr,
        const float* __restrict__ unif_h,
        float* __restrict__ xout, float* __restrict__ hlast) {
    __shared__ _Float16 hd[2][128];
    int b    = blockIdx.x;
    int tid  = threadIdx.x;        // 0..255
    int l    = tid & 63;
    int wv   = tid >> 6;           // 0..3
    int n    = wv * 32 + (l & 31); // hidden column owned
    int half = l >> 5;             // k-half (lanes 0-31: k 0..63, lanes 32-63: k 64..127)

    h2_t w[4][32];
#pragma unroll
    for (int gq = 0; gq < 4; gq++) {
        const _Float16* wr = whh_h + (size_t)(gq * 128 + n) * NH + 64 * half;
#pragma unroll
        for (int i = 0; i < 8; i++) {
            h8_t a = *(const h8_t*)(wr + 8 * i);
#pragma unroll
            for (int q = 0; q < 4; q++)
                w[gq][4 * i + q] = (h2_t){a[2 * q], a[2 * q + 1]};
        }
    }

    float pr = sig(plr[0]);
    float msk;
    {
        float u  = unif_h[b * NH + n];
        float lg = logf(pr + F_EPS) - logf(1.f - pr + F_EPS)
                 + logf(u + F_EPS) - logf(1.f - u + F_EPS);
        float mk = 1.f - sig(lg / F_TEMP);
        msk = mk / (1.f - pr);
    }
    float h = 0.f, c = 0.f;
    if (half == 0) hd[0][n] = (_Float16)0.f;

    // 4 G streams (gate rows n, n+128, n+256, n+384); both halves read the
    // same addresses -> hardware-merged.
    const _Float16* gp0 = Gp + (size_t)(0 * 128 + n) * NMP + (size_t)b * NT;
    const _Float16* gp1 = Gp + (size_t)(1 * 128 + n) * NMP + (size_t)b * NT;
    const _Float16* gp2 = Gp + (size_t)(2 * 128 + n) * NMP + (size_t)b * NT;
    const _Float16* gp3 = Gp + (size_t)(3 * 128 + n) * NMP + (size_t)b * NT;
    float* xo = xout + (size_t)b * NT * NH + n;   // stored by half==0 lanes

    h8_t g0 = *(const h8_t*)(gp0);
    h8_t g1 = *(const h8_t*)(gp1);
    h8_t g2 = *(const h8_t*)(gp2);
    h8_t g3 = *(const h8_t*)(gp3);
    __syncthreads();          // hd[0] init visible

    for (int w8 = 0; w8 < NT / 8; w8++) {
        // pin W_hh in VGPRs (loop-carried asm outputs can't be rematerialized)
#pragma unroll
        for (int gq = 0; gq < 4; gq++)
#pragma unroll
            for (int i = 0; i < 32; i++) asm volatile("" : "+v"(w[gq][i]));
        h8_t n0 = g0, n1 = g1, n2 = g2, n3 = g3;
        if (w8 + 1 < NT / 8) {
            n0 = *(const h8_t*)(gp0 + 8 * (w8 + 1));   // in flight ~8 steps
            n1 = *(const h8_t*)(gp1 + 8 * (w8 + 1));
            n2 = *(const h8_t*)(gp2 + 8 * (w8 + 1));
            n3 = *(const h8_t*)(gp3 + 8 * (w8 + 1));
        }
#pragma unroll
        for (int e = 0; e < 8; e++) {
            const _Float16* hb = &hd[e & 1][64 * half];   // this thread's k-half
            float a0a = 0.f, a0b = 0.f, a1a = 0.f, a1b = 0.f;
            float a2a = 0.f, a2b = 0.f, a3a = 0.f, a3b = 0.f;
#pragma unroll
            for (int i = 0; i < 8; i++) {
                h8_t hv = *(const h8_t*)(hb + 8 * i);     // 2-addr broadcast read
                h2_t h0 = (h2_t){hv[0], hv[1]}, h1v = (h2_t){hv[2], hv[3]};
                h2_t h2v = (h2_t){hv[4], hv[5]}, h3v = (h2_t){hv[6], hv[7]};
                a0a = FDOT2(h0, w[0][4 * i + 0], a0a);
                a0b = FDOT2(h1v, w[0][4 * i + 1], a0b);
                a0a = FDOT2(h2v, w[0][4 * i + 2], a0a);
                a0b = FDOT2(h3v, w[0][4 * i + 3], a0b);
                a1a = FDOT2(h0, w[1][4 * i + 0], a1a);
                a1b = FDOT2(h1v, w[1][4 * i + 1], a1b);
                a1a = FDOT2(h2v, w[1][4 * i + 2], a1a);
                a1b = FDOT2(h3v, w[1][4 * i + 3], a1b);
                a2a = FDOT2(h0, w[2][4 * i + 0], a2a);
                a2b = FDOT2(h1v, w[2][4 * i + 1], a2b);
                a2a = FDOT2(h2v, w[2][4 * i + 2], a2a);
                a2b = FDOT2(h3v, w[2][4 * i + 3], a2b);
                a3a = FDOT2(h0, w[3][4 * i + 0], a3a);
                a3b = FDOT2(h1v, w[3][4 * i + 1], a3b);
                a3a = FDOT2(h2v, w[3][4 * i + 2], a3a);
                a3b = FDOT2(h3v, w[3][4 * i + 3], a3b);
            }
            float s0 = a0a + a0b, s1 = a1a + a1b;
            float s2 = a2a + a2b, s3 = a3a + a3b;
            // combine k-halves (symmetric: both halves end with full sums)
            s0 += __shfl_xor(s0, 32, 64);
            s1 += __shfl_xor(s1, 32, 64);
            s2 += __shfl_xor(s2, 32, 64);
            s3 += __shfl_xor(s3, 32, 64);
            s0 += (float)g0[e];
            s1 += (float)g1[e];
            s2 += (float)g2[e];
            s3 += (float)g3[e];
            float iv = fsig(s0), fv = fsig(s1);
            float gv = ftanh(s2), ov = fsig(s3);
            c = fv * c + iv * gv;
            h = ov * ftanh(c);
            if (half == 0) {
                hd[(e & 1) ^ 1][n] = (_Float16)(h * msk);
                xo[(size_t)(8 * w8 + e) * NH] = h;   // never drained by bar_lds
            }
            bar_lds();         // hd writes visible; next step reads other buffer
        }
        g0 = n0; g1 = n1; g2 = n2; g3 = n3;
    }
    if (half == 0) hlast[(size_t)b * NH + n] = h;
}

extern "C" void kernel_launch(void* const* d_in, const int* in_sizes, int n_in,
                              void* d_out, int out_size, void* d_ws, size_t ws_size,
                              hipStream_t stream) {
    const float* x   = (const float*)d_in[0];
    const float* wih = (const float*)d_in[1];
    const float* whh = (const float*)d_in[2];
    const float* bih = (const float*)d_in[3];
    const float* bhh = (const float*)d_in[4];
    const float* pl  = (const float*)d_in[5];
    const float* plr = (const float*)d_in[6];
    const float* ux  = (const float*)d_in[7];
    const float* uh  = (const float*)d_in[8];

    float* out   = (float*)d_out;
    float* xout  = out;                                 // [B,T,H]
    float* hlast = out + (size_t)NB * NT * NH;          // [B,H]
    float* tail  = hlast + (size_t)NB * NH;             // reg, p, p_rec

    _Float16* G     = (_Float16*)d_ws;                               // [NG][NMP] f16
    _Float16* wih_h = (_Float16*)((char*)d_ws + (size_t)NG * NMP * 2);
    _Float16* whh_h = wih_h + (size_t)NG * ND;
    float*    partial = (float*)(whh_h + (size_t)NG * NH);           // 2 floats

    hipMemsetAsync(partial, 0, 2 * sizeof(float), stream);

    k_convert<<<64, 256, 0, stream>>>(wih, whh, wih_h, whh_h, partial);

    dim3 gg(NM / 128, NG / 128);
    k_gemm<<<gg, 256, 0, stream>>>(x, wih_h, bih, bhh, pl, ux, G);

    k_tail<<<1, 512, 0, stream>>>(bih, bhh, pl, plr, partial, tail);

    k_lstm<<<NB, 256, 0, stream>>>(G, whh_h, plr, uh, xout, hlast);
}